// Round 4
// baseline (592.333 us; speedup 1.0000x reference)
//
#include <hip/hip_runtime.h>
#include <hip/hip_bf16.h>
#include <stdint.h>

#define B_   2
#define S_   2048
#define H_   2048
#define NH_  16
#define HD_  128
#define MTOT (B_*S_)   // 4096

typedef __attribute__((ext_vector_type(8))) short bf16x8;   // 8 bf16 = 4 VGPRs
typedef __attribute__((ext_vector_type(4))) float f32x4;    // MFMA C/D

__device__ __forceinline__ void gload_lds16(const void* g, void* l) {
    __builtin_amdgcn_global_load_lds(
        (const __attribute__((address_space(1))) void*)g,
        (__attribute__((address_space(3))) void*)l, 16, 0, 0);
}

__device__ __forceinline__ unsigned short f2bfu(float x) {
    __hip_bfloat16 h = __float2bfloat16(x);
    return *reinterpret_cast<unsigned short*>(&h);
}

// ---------------------------------------------------------------- casts fp32 -> bf16
__global__ void castk(const float* __restrict__ in, __hip_bfloat16* __restrict__ out, int n4) {
    int i = blockIdx.x * 256 + threadIdx.x;
    if (i < n4) {
        float4 v = *(const float4*)(in + (size_t)i * 4);
        out[(size_t)i*4 + 0] = __float2bfloat16(v.x);
        out[(size_t)i*4 + 1] = __float2bfloat16(v.y);
        out[(size_t)i*4 + 2] = __float2bfloat16(v.z);
        out[(size_t)i*4 + 3] = __float2bfloat16(v.w);
    }
}

__global__ void castw4(const float* __restrict__ w0, const float* __restrict__ w1,
                       const float* __restrict__ w2, const float* __restrict__ w3,
                       __hip_bfloat16* o0, __hip_bfloat16* o1,
                       __hip_bfloat16* o2, __hip_bfloat16* o3, int n4) {
    const float* in; __hip_bfloat16* out;
    switch (blockIdx.y) {
        case 0:  in = w0; out = o0; break;
        case 1:  in = w1; out = o1; break;
        case 2:  in = w2; out = o2; break;
        default: in = w3; out = o3; break;
    }
    int i = blockIdx.x * 256 + threadIdx.x;
    if (i < n4) {
        float4 v = *(const float4*)(in + (size_t)i * 4);
        out[(size_t)i*4 + 0] = __float2bfloat16(v.x);
        out[(size_t)i*4 + 1] = __float2bfloat16(v.y);
        out[(size_t)i*4 + 2] = __float2bfloat16(v.z);
        out[(size_t)i*4 + 3] = __float2bfloat16(v.w);
    }
}

// ---------------------------------------------------------------- shared NT-GEMM body (m97 structure)
template<int OUT_BF16>
__device__ __forceinline__ void gemm_body(const __hip_bfloat16* __restrict__ Ablk,
                                          const __hip_bfloat16* __restrict__ Wblk,
                                          const float* __restrict__ bias,
                                          void* __restrict__ Cout,
                                          int N, int K, int br, int bc)
{
    __shared__ __align__(16) __hip_bfloat16 As[128 * 32];
    __shared__ __align__(16) __hip_bfloat16 Bs[128 * 32];

    const int tid  = threadIdx.x;
    const int wave = tid >> 6, lane = tid & 63;
    const int quad = lane >> 4, l16 = lane & 15;
    const int wr = wave >> 1, wc = wave & 1;

    f32x4 acc[4][4] = {};

    for (int k0 = 0; k0 < K; k0 += 32) {
#pragma unroll
        for (int t = 0; t < 2; ++t) {
            int c = t * 256 + wave * 64 + lane;
            int row = c >> 2, cc = c & 3;
            int base = (t * 256 + wave * 64) * 16;       // wave-uniform
            gload_lds16(Ablk + (size_t)row * K + k0 + cc * 8, (char*)As + base);
            gload_lds16(Wblk + (size_t)row * K + k0 + cc * 8, (char*)Bs + base);
        }
        __syncthreads();

        bf16x8 af[4], bf[4];
#pragma unroll
        for (int i = 0; i < 4; ++i)
            af[i] = *(const bf16x8*)&As[(wr * 64 + i * 16 + l16) * 32 + quad * 8];
#pragma unroll
        for (int j = 0; j < 4; ++j)
            bf[j] = *(const bf16x8*)&Bs[(wc * 64 + j * 16 + l16) * 32 + quad * 8];

#pragma unroll
        for (int i = 0; i < 4; ++i)
#pragma unroll
            for (int j = 0; j < 4; ++j)
                acc[i][j] = __builtin_amdgcn_mfma_f32_16x16x32_bf16(af[i], bf[j], acc[i][j], 0, 0, 0);
        __syncthreads();
    }

#pragma unroll
    for (int i = 0; i < 4; ++i) {
        int row = br * 128 + wr * 64 + i * 16 + quad * 4;
#pragma unroll
        for (int j = 0; j < 4; ++j) {
            int col = bc * 128 + wc * 64 + j * 16 + l16;
            float bv = bias[col];
#pragma unroll
            for (int r = 0; r < 4; ++r) {
                float v = acc[i][j][r] + bv;
                if (OUT_BF16)
                    ((__hip_bfloat16*)Cout)[(size_t)(row + r) * N + col] = __float2bfloat16(v);
                else
                    ((float*)Cout)[(size_t)(row + r) * N + col] = v;
            }
        }
    }
}

// fused Q/K/V projection: grid (48, 32); blockIdx.x selects {Wq,Wk,Wv} and column block
__global__ __launch_bounds__(256)
void gemm_qkv(const __hip_bfloat16* __restrict__ X,
              const __hip_bfloat16* __restrict__ Wq, const __hip_bfloat16* __restrict__ Wk,
              const __hip_bfloat16* __restrict__ Wv,
              const float* __restrict__ bq, const float* __restrict__ bk,
              const float* __restrict__ bv,
              __hip_bfloat16* Qo, __hip_bfloat16* Ko, __hip_bfloat16* Vo)
{
    const int sel = blockIdx.x >> 4;     // 0,1,2
    const int bc  = blockIdx.x & 15;
    const int br  = blockIdx.y;
    const __hip_bfloat16* W = (sel == 0) ? Wq : (sel == 1) ? Wk : Wv;
    const float* bias       = (sel == 0) ? bq : (sel == 1) ? bk : bv;
    __hip_bfloat16* out     = (sel == 0) ? Qo : (sel == 1) ? Ko : Vo;
    gemm_body<1>(X + (size_t)(br * 128) * H_, W + (size_t)(bc * 128) * H_,
                 bias, out, H_, H_, br, bc);
}

// O-projection: fp32 out
__global__ __launch_bounds__(256)
void gemm_out(const __hip_bfloat16* __restrict__ A, const __hip_bfloat16* __restrict__ W,
              const float* __restrict__ bias, float* __restrict__ C)
{
    gemm_body<0>(A + (size_t)(blockIdx.y * 128) * H_, W + (size_t)(blockIdx.x * 128) * H_,
                 bias, C, H_, H_, blockIdx.y, blockIdx.x);
}

// ---------------------------------------------------------------- flash attention v4
// 128-row Q tiles, S^T orientation (per-lane softmax), XCD-pinned, K dbuf via global_load_lds
#define VSTR 72    // VsT row stride (64+8)
#define PSTR 72    // Ps row stride (64+8)

__global__ __launch_bounds__(256)
void attn_kernel(const __hip_bfloat16* __restrict__ Q,
                 const __hip_bfloat16* __restrict__ K,
                 const __hip_bfloat16* __restrict__ V,
                 __hip_bfloat16* __restrict__ O)
{
    __shared__ __align__(16) char KsB[2][64 * 256];            // 32 KB, XOR-swizzled 16B chunks
    __shared__ __align__(16) __hip_bfloat16 VsT[128 * VSTR];   // 18 KB, V transposed [d][n]
    __shared__ __align__(16) __hip_bfloat16 Ps[4][16 * PSTR];  // 9 KB, per-wave P[m][n]

    const int tid  = threadIdx.x;
    const int wave = tid >> 6, lane = tid & 63;
    const int quad = lane >> 4, l16 = lane & 15;

    // XCD-pinning: all 16 blocks of one (b,h) on one XCD (RR heuristic)
    const int lid  = blockIdx.x;                 // 0..511
    const int xcd  = lid & 7;
    const int slot = lid >> 3;                   // 0..63
    const int bh   = ((slot >> 4) << 3) | xcd;   // 0..31
    const int pr   = slot & 15;                  // pair index 0..15
    const int b    = bh >> 4, h = bh & 15;

    const size_t headoff = (size_t)b * S_ * H_ + (size_t)h * HD_;
    const __hip_bfloat16* Qp = Q + headoff;
    const __hip_bfloat16* Kp = K + headoff;
    const __hip_bfloat16* Vp = V + headoff;

    const float scale = 0.08838834764831843f;    // 1/sqrt(128)

    for (int which = 0; which < 2; ++which) {
        const int qt = which ? pr : 15 - pr;     // pair-balanced: (2(15-pr)+2)+(2pr+2)=34 iters
        const int qbase = qt * 128;
        const int row0[2] = { qbase + wave * 32, qbase + wave * 32 + 16 };

        bf16x8 qf[2][4];
#pragma unroll
        for (int g = 0; g < 2; ++g)
#pragma unroll
            for (int kd = 0; kd < 4; ++kd)
                qf[g][kd] = *(const bf16x8*)(Qp + (size_t)(row0[g] + l16) * H_ + kd * 32 + quad * 8);

        f32x4 oacc[2][8] = {};
        float mi[2] = { -1e30f, -1e30f }, li[2] = { 0.0f, 0.0f };

        const int nkb = 2 * qt + 2;
        int bb = 0;

        // ---- prologue: stage kb=0 (K async -> KsB[0]; V via regs -> VsT)
        {
#pragma unroll
            for (int t = 0; t < 4; ++t) {
                int c = wave * 256 + t * 64 + lane;
                int row = c >> 4, pos = c & 15;
                int g = pos ^ (row & 7);
                gload_lds16(Kp + (size_t)row * H_ + g * 8, &KsB[0][wave * 4096 + t * 1024]);
            }
            float4 vr[4];
#pragma unroll
            for (int t = 0; t < 4; ++t) {
                int c = t * 256 + tid;
                vr[t] = *(const float4*)(Vp + (size_t)(c & 63) * H_ + (c >> 6) * 8);
            }
            __syncthreads();
#pragma unroll
            for (int t = 0; t < 4; ++t) {
                int c = t * 256 + tid;
                const __hip_bfloat16* vv = (const __hip_bfloat16*)&vr[t];
                int n = c & 63, cc = c >> 6;
#pragma unroll
                for (int i = 0; i < 8; ++i)
                    VsT[(cc * 8 + i) * VSTR + n] = vv[i];
            }
            __syncthreads();
        }

        for (int kb = 0; kb < nkb; ++kb) {
            const bool more = (kb + 1 < nkb);
            const int nb = bb ^ 1;

            float4 vr2[4];
            if (more) {
                const __hip_bfloat16* Kn = Kp + (size_t)(kb + 1) * 64 * H_;
                const __hip_bfloat16* Vn = Vp + (size_t)(kb + 1) * 64 * H_;
#pragma unroll
                for (int t = 0; t < 4; ++t) {
                    int c = wave * 256 + t * 64 + lane;
                    int row = c >> 4, pos = c & 15;
                    int g = pos ^ (row & 7);
                    gload_lds16(Kn + (size_t)row * H_ + g * 8, &KsB[nb][wave * 4096 + t * 1024]);
                }
#pragma unroll
                for (int t = 0; t < 4; ++t) {
                    int c = t * 256 + tid;
                    vr2[t] = *(const float4*)(Vn + (size_t)(c & 63) * H_ + (c >> 6) * 8);
                }
            }

            // active = this 16-query group has any unmasked keys in this K-tile (wave-uniform)
            const bool act[2] = { kb * 64 <= row0[0] + 15, kb * 64 <= row0[1] + 15 };

            // ---- S^T tile: D[n][m], A = K-frag, B = Q-frag; kf shared across both groups
            f32x4 s0[4] = {}, s1[4] = {};
#pragma unroll
            for (int cb = 0; cb < 4; ++cb) {
#pragma unroll
                for (int kd = 0; kd < 4; ++kd) {
                    int row = cb * 16 + l16;
                    int pos = (4 * kd + quad) ^ (l16 & 7);
                    bf16x8 kf = *(const bf16x8*)&KsB[bb][row * 256 + pos * 16];
                    if (act[0]) s0[cb] = __builtin_amdgcn_mfma_f32_16x16x32_bf16(kf, qf[0][kd], s0[cb], 0, 0, 0);
                    if (act[1]) s1[cb] = __builtin_amdgcn_mfma_f32_16x16x32_bf16(kf, qf[1][kd], s1[cb], 0, 0, 0);
                }
            }

            // ---- per group: per-lane softmax (lane owns query m = row0[g]+l16) + PV
#pragma unroll
            for (int g = 0; g < 2; ++g) {
                if (!act[g]) continue;
                f32x4* sacc = g ? s1 : s0;
                const bool domask = (kb * 64 + 63 > row0[g]);
                const int mg = row0[g] + l16;

                float p[4][4];
                float tm = -1e30f;
#pragma unroll
                for (int cb = 0; cb < 4; ++cb)
#pragma unroll
                    for (int r = 0; r < 4; ++r) {
                        float s = sacc[cb][r] * scale;
                        if (domask) {
                            int ng = kb * 64 + cb * 16 + quad * 4 + r;
                            if (ng > mg) s = -1e30f;
                        }
                        p[cb][r] = s;
                        tm = fmaxf(tm, s);
                    }
                tm = fmaxf(tm, __shfl_xor(tm, 16));
                tm = fmaxf(tm, __shfl_xor(tm, 32));
                float mnew = fmaxf(mi[g], tm);
                float sum = 0.0f;
#pragma unroll
                for (int cb = 0; cb < 4; ++cb)
#pragma unroll
                    for (int r = 0; r < 4; ++r) {
                        float e = __expf(p[cb][r] - mnew);
                        p[cb][r] = e;
                        sum += e;
                    }
                sum += __shfl_xor(sum, 16);
                sum += __shfl_xor(sum, 32);
                float alpha = __expf(mi[g] - mnew);
                li[g] = li[g] * alpha + sum;
                mi[g] = mnew;

                // broadcast alpha from lane (l16 = quad*4+r) to rescale C-layout oacc rows
                float ar[4];
#pragma unroll
                for (int r = 0; r < 4; ++r)
                    ar[r] = __shfl(alpha, quad * 4 + r);
#pragma unroll
                for (int db = 0; db < 8; ++db)
#pragma unroll
                    for (int r = 0; r < 4; ++r)
                        oacc[g][db][r] *= ar[r];

                // ---- P[m][n] -> Ps (packed b64 over 4 consecutive keys), wave-private
#pragma unroll
                for (int cb = 0; cb < 4; ++cb) {
                    ushort4 pk;
                    pk.x = f2bfu(p[cb][0]); pk.y = f2bfu(p[cb][1]);
                    pk.z = f2bfu(p[cb][2]); pk.w = f2bfu(p[cb][3]);
                    *(ushort4*)&Ps[wave][l16 * PSTR + cb * 16 + quad * 4] = pk;
                }

                // ---- O[g] += P @ V
#pragma unroll
                for (int ks = 0; ks < 2; ++ks) {
                    bf16x8 pf = *(const bf16x8*)&Ps[wave][l16 * PSTR + ks * 32 + quad * 8];
#pragma unroll
                    for (int db = 0; db < 8; ++db) {
                        bf16x8 vf = *(const bf16x8*)&VsT[(db * 16 + l16) * VSTR + ks * 32 + quad * 8];
                        oacc[g][db] = __builtin_amdgcn_mfma_f32_16x16x32_bf16(pf, vf, oacc[g][db], 0, 0, 0);
                    }
                }
            }

            // ---- stage prefetched V (single-buffered VsT needs the barrier pair)
            if (more) {
                __syncthreads();
#pragma unroll
                for (int t = 0; t < 4; ++t) {
                    int c = t * 256 + tid;
                    const __hip_bfloat16* vv = (const __hip_bfloat16*)&vr2[t];
                    int n = c & 63, cc = c >> 6;
#pragma unroll
                    for (int i = 0; i < 8; ++i)
                        VsT[(cc * 8 + i) * VSTR + n] = vv[i];
                }
                __syncthreads();
            }
            bb = nb;
        }

        // ---- epilogue: li broadcast per C-row, normalize, store
#pragma unroll
        for (int g = 0; g < 2; ++g) {
            float lr[4];
#pragma unroll
            for (int r = 0; r < 4; ++r)
                lr[r] = __shfl(li[g], quad * 4 + r);
#pragma unroll
            for (int db = 0; db < 8; ++db)
#pragma unroll
                for (int r = 0; r < 4; ++r) {
                    float v = oacc[g][db][r] / lr[r];
                    size_t row = (size_t)b * S_ + row0[g] + quad * 4 + r;
                    O[row * H_ + h * HD_ + db * 16 + l16] = __float2bfloat16(v);
                }
        }
        __syncthreads();   // all waves done with KsB/VsT before next which's prologue
    }
}

// ---------------------------------------------------------------- launcher
extern "C" void kernel_launch(void* const* d_in, const int* in_sizes, int n_in,
                              void* d_out, int out_size, void* d_ws, size_t ws_size,
                              hipStream_t stream)
{
    const float* hs = (const float*)d_in[0];
    const float* Wq = (const float*)d_in[2];
    const float* bq = (const float*)d_in[3];
    const float* Wk = (const float*)d_in[4];
    const float* bk = (const float*)d_in[5];
    const float* Wv = (const float*)d_in[6];
    const float* bv = (const float*)d_in[7];
    const float* Wo = (const float*)d_in[8];
    const float* bo = (const float*)d_in[9];

    const size_t szX = (size_t)MTOT * H_;
    const size_t szW = (size_t)H_ * H_;

    __hip_bfloat16* Xbf = (__hip_bfloat16*)d_ws;   // reused as attention output
    __hip_bfloat16* Wqb = Xbf + szX;
    __hip_bfloat16* Wkb = Wqb + szW;
    __hip_bfloat16* Wvb = Wkb + szW;
    __hip_bfloat16* Wob = Wvb + szW;
    __hip_bfloat16* Qb  = Wob + szW;
    __hip_bfloat16* Kb  = Qb + szX;
    __hip_bfloat16* Vb  = Kb + szX;

    castk<<<(int)((szX/4 + 255)/256), 256, 0, stream>>>(hs, Xbf, (int)(szX/4));
    dim3 wgrid((unsigned)((szW/4 + 255)/256), 4);
    castw4<<<wgrid, 256, 0, stream>>>(Wq, Wk, Wv, Wo, Wqb, Wkb, Wvb, Wob, (int)(szW/4));

    gemm_qkv<<<dim3(48, 32), 256, 0, stream>>>(Xbf, Wqb, Wkb, Wvb, bq, bk, bv, Qb, Kb, Vb);

    attn_kernel<<<dim3(512), 256, 0, stream>>>(Qb, Kb, Vb, Xbf);

    gemm_out<<<dim3(16, 32), 256, 0, stream>>>(Xbf, Wob, bo, (float*)d_out);
}

// Round 5
// 418.456 us; speedup vs baseline: 1.4155x; 1.4155x over previous
//
#include <hip/hip_runtime.h>
#include <hip/hip_bf16.h>
#include <stdint.h>

#define B_   2
#define S_   2048
#define H_   2048
#define NH_  16
#define HD_  128
#define MTOT (B_*S_)   // 4096

typedef __attribute__((ext_vector_type(8))) short bf16x8;   // 8 bf16 = 4 VGPRs
typedef __attribute__((ext_vector_type(4))) float f32x4;    // MFMA C/D

__device__ __forceinline__ void gload_lds16(const void* g, void* l) {
    __builtin_amdgcn_global_load_lds(
        (const __attribute__((address_space(1))) void*)g,
        (__attribute__((address_space(3))) void*)l, 16, 0, 0);
}

__device__ __forceinline__ unsigned short f2bfu(float x) {
    __hip_bfloat16 h = __float2bfloat16(x);
    return *reinterpret_cast<unsigned short*>(&h);
}

// ---------------------------------------------------------------- casts fp32 -> bf16
__global__ void castk(const float* __restrict__ in, __hip_bfloat16* __restrict__ out, int n4) {
    int i = blockIdx.x * 256 + threadIdx.x;
    if (i < n4) {
        float4 v = *(const float4*)(in + (size_t)i * 4);
        out[(size_t)i*4 + 0] = __float2bfloat16(v.x);
        out[(size_t)i*4 + 1] = __float2bfloat16(v.y);
        out[(size_t)i*4 + 2] = __float2bfloat16(v.z);
        out[(size_t)i*4 + 3] = __float2bfloat16(v.w);
    }
}

__global__ void castw4(const float* __restrict__ w0, const float* __restrict__ w1,
                       const float* __restrict__ w2, const float* __restrict__ w3,
                       __hip_bfloat16* o0, __hip_bfloat16* o1,
                       __hip_bfloat16* o2, __hip_bfloat16* o3, int n4) {
    const float* in; __hip_bfloat16* out;
    switch (blockIdx.y) {
        case 0:  in = w0; out = o0; break;
        case 1:  in = w1; out = o1; break;
        case 2:  in = w2; out = o2; break;
        default: in = w3; out = o3; break;
    }
    int i = blockIdx.x * 256 + threadIdx.x;
    if (i < n4) {
        float4 v = *(const float4*)(in + (size_t)i * 4);
        out[(size_t)i*4 + 0] = __float2bfloat16(v.x);
        out[(size_t)i*4 + 1] = __float2bfloat16(v.y);
        out[(size_t)i*4 + 2] = __float2bfloat16(v.z);
        out[(size_t)i*4 + 3] = __float2bfloat16(v.w);
    }
}

// ---------------------------------------------------------------- shared NT-GEMM body (m97 structure)
template<int OUT_BF16>
__device__ __forceinline__ void gemm_body(const __hip_bfloat16* __restrict__ Ablk,
                                          const __hip_bfloat16* __restrict__ Wblk,
                                          const float* __restrict__ bias,
                                          void* __restrict__ Cout,
                                          int N, int K, int br, int bc)
{
    __shared__ __align__(16) __hip_bfloat16 As[128 * 32];
    __shared__ __align__(16) __hip_bfloat16 Bs[128 * 32];

    const int tid  = threadIdx.x;
    const int wave = tid >> 6, lane = tid & 63;
    const int quad = lane >> 4, l16 = lane & 15;
    const int wr = wave >> 1, wc = wave & 1;

    f32x4 acc[4][4] = {};

    for (int k0 = 0; k0 < K; k0 += 32) {
#pragma unroll
        for (int t = 0; t < 2; ++t) {
            int c = t * 256 + wave * 64 + lane;
            int row = c >> 2, cc = c & 3;
            int base = (t * 256 + wave * 64) * 16;       // wave-uniform
            gload_lds16(Ablk + (size_t)row * K + k0 + cc * 8, (char*)As + base);
            gload_lds16(Wblk + (size_t)row * K + k0 + cc * 8, (char*)Bs + base);
        }
        __syncthreads();

        bf16x8 af[4], bf[4];
#pragma unroll
        for (int i = 0; i < 4; ++i)
            af[i] = *(const bf16x8*)&As[(wr * 64 + i * 16 + l16) * 32 + quad * 8];
#pragma unroll
        for (int j = 0; j < 4; ++j)
            bf[j] = *(const bf16x8*)&Bs[(wc * 64 + j * 16 + l16) * 32 + quad * 8];

#pragma unroll
        for (int i = 0; i < 4; ++i)
#pragma unroll
            for (int j = 0; j < 4; ++j)
                acc[i][j] = __builtin_amdgcn_mfma_f32_16x16x32_bf16(af[i], bf[j], acc[i][j], 0, 0, 0);
        __syncthreads();
    }

#pragma unroll
    for (int i = 0; i < 4; ++i) {
        int row = br * 128 + wr * 64 + i * 16 + quad * 4;
#pragma unroll
        for (int j = 0; j < 4; ++j) {
            int col = bc * 128 + wc * 64 + j * 16 + l16;
            float bv = bias[col];
#pragma unroll
            for (int r = 0; r < 4; ++r) {
                float v = acc[i][j][r] + bv;
                if (OUT_BF16)
                    ((__hip_bfloat16*)Cout)[(size_t)(row + r) * N + col] = __float2bfloat16(v);
                else
                    ((float*)Cout)[(size_t)(row + r) * N + col] = v;
            }
        }
    }
}

// fused Q/K/V projection: grid (48, 32); blockIdx.x selects {Wq,Wk,Wv} and column block
__global__ __launch_bounds__(256)
void gemm_qkv(const __hip_bfloat16* __restrict__ X,
              const __hip_bfloat16* __restrict__ Wq, const __hip_bfloat16* __restrict__ Wk,
              const __hip_bfloat16* __restrict__ Wv,
              const float* __restrict__ bq, const float* __restrict__ bk,
              const float* __restrict__ bv,
              __hip_bfloat16* Qo, __hip_bfloat16* Ko, __hip_bfloat16* Vo)
{
    const int sel = blockIdx.x >> 4;     // 0,1,2
    const int bc  = blockIdx.x & 15;
    const int br  = blockIdx.y;
    const __hip_bfloat16* W = (sel == 0) ? Wq : (sel == 1) ? Wk : Wv;
    const float* bias       = (sel == 0) ? bq : (sel == 1) ? bk : bv;
    __hip_bfloat16* out     = (sel == 0) ? Qo : (sel == 1) ? Ko : Vo;
    gemm_body<1>(X + (size_t)(br * 128) * H_, W + (size_t)(bc * 128) * H_,
                 bias, out, H_, H_, br, bc);
}

// O-projection: fp32 out
__global__ __launch_bounds__(256)
void gemm_out(const __hip_bfloat16* __restrict__ A, const __hip_bfloat16* __restrict__ W,
              const float* __restrict__ bias, float* __restrict__ C)
{
    gemm_body<0>(A + (size_t)(blockIdx.y * 128) * H_, W + (size_t)(blockIdx.x * 128) * H_,
                 bias, C, H_, H_, blockIdx.y, blockIdx.x);
}

// ---------------------------------------------------------------- flash attention v5
// v3 structure (64-row q-tiles, disjoint pairs {31-p,p}, XCD-pinned, K dbuf via global_load_lds)
// + S^T orientation: per-lane softmax (lane owns query l16), packed b64 P writes.
#define VSTR 72    // VsT row stride (64+8)
#define PSTR 72    // Ps row stride (64+8)

__global__ __launch_bounds__(256)
void attn_kernel(const __hip_bfloat16* __restrict__ Q,
                 const __hip_bfloat16* __restrict__ K,
                 const __hip_bfloat16* __restrict__ V,
                 __hip_bfloat16* __restrict__ O)
{
    __shared__ __align__(16) char KsB[2][64 * 256];            // 32 KB, XOR-swizzled 16B chunks
    __shared__ __align__(16) __hip_bfloat16 VsT[128 * VSTR];   // 18 KB, V transposed [d][n]
    __shared__ __align__(16) __hip_bfloat16 Ps[4][16 * PSTR];  // 9 KB, per-wave P^T[query][key]

    const int tid  = threadIdx.x;
    const int wave = tid >> 6, lane = tid & 63;
    const int quad = lane >> 4, l16 = lane & 15;

    // XCD-pinning: all 16 blocks of one (b,h) on one XCD (RR heuristic)
    const int lid  = blockIdx.x;                 // 0..511
    const int xcd  = lid & 7;
    const int slot = lid >> 3;                   // 0..63
    const int bh   = ((slot >> 4) << 3) | xcd;   // 0..31
    const int pr   = slot & 15;                  // pair index 0..15
    const int b    = bh >> 4, h = bh & 15;

    const size_t headoff = (size_t)b * S_ * H_ + (size_t)h * HD_;
    const __hip_bfloat16* Qp = Q + headoff;
    const __hip_bfloat16* Kp = K + headoff;
    const __hip_bfloat16* Vp = V + headoff;

    const float scale = 0.08838834764831843f;    // 1/sqrt(128)

    for (int which = 0; which < 2; ++which) {
        const int qb = which ? pr : 31 - pr;     // disjoint: {31..16} then {0..15}
        const int qrow_local = wave * 16;
        const int qrow = qb * 64 + qrow_local;

        // Q fragment = MFMA B operand (same lane mapping as A): rows qrow+l16
        bf16x8 qf[4];
#pragma unroll
        for (int kd = 0; kd < 4; ++kd)
            qf[kd] = *(const bf16x8*)(Qp + (size_t)(qrow + l16) * H_ + kd * 32 + quad * 8);

        f32x4 oacc[8] = {};
        float mi = -1e30f, li = 0.0f;            // per-lane: query qrow + l16

        int bb = 0;

        // ---- prologue: stage kb=0 (K async -> KsB[0]; V via regs -> VsT)
        {
#pragma unroll
            for (int t = 0; t < 4; ++t) {
                int c = wave * 256 + t * 64 + lane;
                int row = c >> 4, pos = c & 15;
                int g = pos ^ (row & 7);
                gload_lds16(Kp + (size_t)row * H_ + g * 8, &KsB[0][wave * 4096 + t * 1024]);
            }
            float4 vr[4];
#pragma unroll
            for (int t = 0; t < 4; ++t) {
                int c = t * 256 + tid;
                vr[t] = *(const float4*)(Vp + (size_t)(c & 63) * H_ + (c >> 6) * 8);
            }
            __syncthreads();
#pragma unroll
            for (int t = 0; t < 4; ++t) {
                int c = t * 256 + tid;
                const __hip_bfloat16* vv = (const __hip_bfloat16*)&vr[t];
                int n = c & 63, cc = c >> 6;
#pragma unroll
                for (int i = 0; i < 8; ++i)
                    VsT[(cc * 8 + i) * VSTR + n] = vv[i];
            }
            __syncthreads();
        }

        for (int kb = 0; kb <= qb; ++kb) {
            const bool more = (kb < qb);
            const int nb = bb ^ 1;

            float4 vr2[4];
            if (more) {
                const __hip_bfloat16* Kn = Kp + (size_t)(kb + 1) * 64 * H_;
                const __hip_bfloat16* Vn = Vp + (size_t)(kb + 1) * 64 * H_;
#pragma unroll
                for (int t = 0; t < 4; ++t) {
                    int c = wave * 256 + t * 64 + lane;
                    int row = c >> 4, pos = c & 15;
                    int g = pos ^ (row & 7);
                    gload_lds16(Kn + (size_t)row * H_ + g * 8, &KsB[nb][wave * 4096 + t * 1024]);
                }
#pragma unroll
                for (int t = 0; t < 4; ++t) {
                    int c = t * 256 + tid;
                    vr2[t] = *(const float4*)(Vn + (size_t)(c & 63) * H_ + (c >> 6) * 8);
                }
            }

            // ---- S^T tile: D[key][query] = K·Q^T ; A = K-frag, B = Q-frag
            f32x4 sacc[4] = {};
#pragma unroll
            for (int cb = 0; cb < 4; ++cb) {
#pragma unroll
                for (int kd = 0; kd < 4; ++kd) {
                    int row = cb * 16 + l16;
                    int pos = (4 * kd + quad) ^ (l16 & 7);
                    bf16x8 kf = *(const bf16x8*)&KsB[bb][row * 256 + pos * 16];
                    sacc[cb] = __builtin_amdgcn_mfma_f32_16x16x32_bf16(kf, qf[kd], sacc[cb], 0, 0, 0);
                }
            }

            // lane owns query (qrow + l16); its 16 scores are keys cb*16 + quad*4 + r
            const bool diag = (kb == qb);
            float p[4][4];
            float tm = -1e30f;
#pragma unroll
            for (int cb = 0; cb < 4; ++cb)
#pragma unroll
                for (int r = 0; r < 4; ++r) {
                    float s = sacc[cb][r] * scale;
                    if (diag) {
                        int keyl = cb * 16 + quad * 4 + r;        // within-tile key
                        if (keyl > qrow_local + l16) s = -1e30f;  // within-tile query
                    }
                    p[cb][r] = s;
                    tm = fmaxf(tm, s);
                }
            // reduce across the 4 quads holding this query (lanes l16, l16+16, +32, +48)
            tm = fmaxf(tm, __shfl_xor(tm, 16));
            tm = fmaxf(tm, __shfl_xor(tm, 32));
            float mnew = fmaxf(mi, tm);
            float sum = 0.0f;
#pragma unroll
            for (int cb = 0; cb < 4; ++cb)
#pragma unroll
                for (int r = 0; r < 4; ++r) {
                    float e = __expf(p[cb][r] - mnew);
                    p[cb][r] = e;
                    sum += e;
                }
            sum += __shfl_xor(sum, 16);
            sum += __shfl_xor(sum, 32);
            float alpha = __expf(mi - mnew);
            li = li * alpha + sum;
            mi = mnew;

            // rescale O (C-layout: reg r = query quad*4+r): broadcast alpha per row
            float ar[4];
#pragma unroll
            for (int r = 0; r < 4; ++r)
                ar[r] = __shfl(alpha, quad * 4 + r);
#pragma unroll
            for (int db = 0; db < 8; ++db)
#pragma unroll
                for (int r = 0; r < 4; ++r)
                    oacc[db][r] *= ar[r];

            // ---- P^T[query][key] -> Ps, packed b64 over 4 consecutive keys (wave-private)
#pragma unroll
            for (int cb = 0; cb < 4; ++cb) {
                ushort4 pk;
                pk.x = f2bfu(p[cb][0]); pk.y = f2bfu(p[cb][1]);
                pk.z = f2bfu(p[cb][2]); pk.w = f2bfu(p[cb][3]);
                *(ushort4*)&Ps[wave][l16 * PSTR + cb * 16 + quad * 4] = pk;
            }

            // ---- O += P^T @ V : A = P^T (m=query=l16, k=key), B = VsT (n=d, k=key)
#pragma unroll
            for (int ks = 0; ks < 2; ++ks) {
                bf16x8 pf = *(const bf16x8*)&Ps[wave][l16 * PSTR + ks * 32 + quad * 8];
#pragma unroll
                for (int db = 0; db < 8; ++db) {
                    bf16x8 vf = *(const bf16x8*)&VsT[(db * 16 + l16) * VSTR + ks * 32 + quad * 8];
                    oacc[db] = __builtin_amdgcn_mfma_f32_16x16x32_bf16(pf, vf, oacc[db], 0, 0, 0);
                }
            }

            // ---- stage prefetched V (single-buffered VsT needs the barrier pair)
            if (more) {
                __syncthreads();
#pragma unroll
                for (int t = 0; t < 4; ++t) {
                    int c = t * 256 + tid;
                    const __hip_bfloat16* vv = (const __hip_bfloat16*)&vr2[t];
                    int n = c & 63, cc = c >> 6;
#pragma unroll
                    for (int i = 0; i < 8; ++i)
                        VsT[(cc * 8 + i) * VSTR + n] = vv[i];
                }
                __syncthreads();
            }
            bb = nb;
        }

        // ---- epilogue: O[query=qrow+quad*4+r][d=db*16+l16] ; li broadcast per row
        float lr[4];
#pragma unroll
        for (int r = 0; r < 4; ++r)
            lr[r] = __shfl(li, quad * 4 + r);
#pragma unroll
        for (int db = 0; db < 8; ++db)
#pragma unroll
            for (int r = 0; r < 4; ++r) {
                float v = oacc[db][r] / lr[r];
                size_t row = (size_t)b * S_ + qrow + quad * 4 + r;
                O[row * H_ + h * HD_ + db * 16 + l16] = __float2bfloat16(v);
            }
        __syncthreads();   // all waves done with KsB/VsT before next which's prologue
    }
}

// ---------------------------------------------------------------- launcher
extern "C" void kernel_launch(void* const* d_in, const int* in_sizes, int n_in,
                              void* d_out, int out_size, void* d_ws, size_t ws_size,
                              hipStream_t stream)
{
    const float* hs = (const float*)d_in[0];
    const float* Wq = (const float*)d_in[2];
    const float* bq = (const float*)d_in[3];
    const float* Wk = (const float*)d_in[4];
    const float* bk = (const float*)d_in[5];
    const float* Wv = (const float*)d_in[6];
    const float* bv = (const float*)d_in[7];
    const float* Wo = (const float*)d_in[8];
    const float* bo = (const float*)d_in[9];

    const size_t szX = (size_t)MTOT * H_;
    const size_t szW = (size_t)H_ * H_;

    __hip_bfloat16* Xbf = (__hip_bfloat16*)d_ws;   // reused as attention output
    __hip_bfloat16* Wqb = Xbf + szX;
    __hip_bfloat16* Wkb = Wqb + szW;
    __hip_bfloat16* Wvb = Wkb + szW;
    __hip_bfloat16* Wob = Wvb + szW;
    __hip_bfloat16* Qb  = Wob + szW;
    __hip_bfloat16* Kb  = Qb + szX;
    __hip_bfloat16* Vb  = Kb + szX;

    castk<<<(int)((szX/4 + 255)/256), 256, 0, stream>>>(hs, Xbf, (int)(szX/4));
    dim3 wgrid((unsigned)((szW/4 + 255)/256), 4);
    castw4<<<wgrid, 256, 0, stream>>>(Wq, Wk, Wv, Wo, Wqb, Wkb, Wvb, Wob, (int)(szW/4));

    gemm_qkv<<<dim3(48, 32), 256, 0, stream>>>(Xbf, Wqb, Wkb, Wvb, bq, bk, bv, Qb, Kb, Vb);

    attn_kernel<<<dim3(512), 256, 0, stream>>>(Qb, Kb, Vb, Xbf);

    gemm_out<<<dim3(16, 32), 256, 0, stream>>>(Xbf, Wob, bo, (float*)d_out);
}